// Round 16
// baseline (338.009 us; speedup 1.0000x reference)
//
#include <hip/hip_runtime.h>
#include <cstdint>

// ---------------------------------------------------------------------------
// AnaphoricityScorer: scores = rough + FFNN([a, b, a*b, pw] @ W1 -> leaky -> W_out)
// Factorized: h = Ha[batch] + Hb[idx] + (a*b|pw)@W1cd + b1
// R16: 128x128 PER-WAVE register tile (bytes/MFMA 384 -> 256).
//   R15 closed the model: perf is pinned at the L1->VGPR return ceiling
//   (~66 B/cyc/CU) by per-wave REQUESTED bytes (sharing doesn't dedupe).
//   16 frags/kc now feed 64 MFMAs; total requested bytes 2.6 -> 1.74 GB;
//   return floor ~44us = MFMA floor ~46us (balanced). acc 256 + operands
//   ~130 regs -> 1 wave/SIMD (launch_bounds(256,1)); ILP-only latency
//   hiding via 2-deep ping-pong (1-kc issue-ahead = full-round cover).
//   Operand layouts: [tile128][kc][frag8][lane64][8e] -- 8 frags contiguous
//   per kc -> single base pointer + imm offsets. Same template for Ha+Hb.
// ---------------------------------------------------------------------------

typedef short short8 __attribute__((ext_vector_type(8)));
typedef float f32x4 __attribute__((ext_vector_type(4)));

#define PT2_RT 278528ULL  // 34 kc * 8192 B per 128-row pair tile
#define MT2_RT 262144ULL  // 32 kc * 8192 B per 128-row mention tile
#define BT2_CT 802816ULL  // 98 kc * 8192 B per 128-col W1 tile

static __device__ __forceinline__ unsigned short f2bf(float x) {
  union { float f; unsigned u; } v; v.f = x;
  unsigned r = v.u + 0x7fffu + ((v.u >> 16) & 1u);  // RNE
  return (unsigned short)(r >> 16);
}
static __device__ __forceinline__ float bf2f(unsigned short u) {
  union { unsigned u; float f; } v; v.u = ((unsigned)u) << 16;
  return v.f;
}

// W1 [3136][1024] f32 -> Bt2 [8 ct][98 kc][8 nf][64 lane][8 e] bf16
__global__ void k_packW(const float* __restrict__ W1, unsigned short* __restrict__ Bt2) {
  __shared__ float t[64][65];
  int k0 = blockIdx.x * 64, n0 = blockIdx.y * 64;
  int c = threadIdx.x & 63, r4 = threadIdx.x >> 6;
#pragma unroll
  for (int rr = 0; rr < 16; ++rr) {
    int r = rr * 4 + r4;
    t[r][c] = W1[(size_t)(k0 + r) * 1024 + n0 + c];
  }
  __syncthreads();
#pragma unroll
  for (int qq = 0; qq < 2; ++qq) {
    int q = threadIdx.x * 2 + qq;
    int cc = q >> 3, rg = q & 7;
    short8 v;
#pragma unroll
    for (int e = 0; e < 8; ++e) v[e] = (short)f2bf(t[rg * 8 + e][cc]);
    int col = n0 + cc;
    int ct = col >> 7, nf = (col >> 4) & 7;
    int kc = (k0 >> 5) + (rg >> 2);
    int ln = (col & 15) + ((rg & 3) << 4);
    *(short8*)((char*)Bt2 + (size_t)ct * BT2_CT + (size_t)kc * 8192 + nf * 1024 + ln * 16) = v;
  }
}

__global__ void k_cvt(const float* __restrict__ s, unsigned short* __restrict__ d, int n4) {
  int i = blockIdx.x * 256 + threadIdx.x;
  if (i < n4) {
    float4 v = ((const float4*)s)[i];
    ushort4 o; o.x = f2bf(v.x); o.y = f2bf(v.y); o.z = f2bf(v.z); o.w = f2bf(v.w);
    ((ushort4*)d)[i] = o;
  }
}

// mentions -> Mt2 [72 rt][32 kc][8 mf][64][8]; global rows: 0..8191 allm, then am.
__global__ void k_packM(const float* __restrict__ am, const float* __restrict__ allm,
                        unsigned short* __restrict__ Mt2) {
  int bid = blockIdx.x, t = threadIdx.x;  // 576 blocks = one 16-row frag each
  int rt = bid >> 3, mf = bid & 7;
  int pf = t & 15, oct = (t >> 4) & 3, kcl = t >> 6;
  int grow = bid * 16 + pf;
  const float* row = (grow < 8192) ? (allm + (size_t)grow * 1024)
                                   : (am + (size_t)(grow - 8192) * 1024);
  char* dst = (char*)Mt2 + (size_t)rt * MT2_RT + mf * 1024 + (t & 63) * 16;
#pragma unroll
  for (int pass = 0; pass < 8; ++pass) {
    int kc = pass * 4 + kcl;
    int k = kc * 32 + oct * 8;
    float4 v0 = *(const float4*)(row + k);
    float4 v1 = *(const float4*)(row + k + 4);
    short8 o;
    o[0] = (short)f2bf(v0.x); o[1] = (short)f2bf(v0.y);
    o[2] = (short)f2bf(v0.z); o[3] = (short)f2bf(v0.w);
    o[4] = (short)f2bf(v1.x); o[5] = (short)f2bf(v1.y);
    o[6] = (short)f2bf(v1.z); o[7] = (short)f2bf(v1.w);
    *(short8*)(dst + (size_t)kc * 8192) = o;
  }
}

// Pair tiles -> Pt2 [400 rt][34 kc][8 mf][64][8]. Block = one 16-pair frag.
__global__ void k_pairs(const unsigned short* __restrict__ Abm,
                        const unsigned short* __restrict__ Aball,
                        const float* __restrict__ pw, const int* __restrict__ idx,
                        unsigned short* __restrict__ Pt2) {
  __shared__ int g16[16];
  int bid = blockIdx.x, t = threadIdx.x;  // 3200 blocks
  int rt = bid >> 3, mf = bid & 7;
  int p0 = bid * 16;
  if (t < 16) g16[t] = idx[p0 + t];
  __syncthreads();
  int pf = t & 15, oct = (t >> 4) & 3, kcl = t >> 6;
  int p = p0 + pf;
  const unsigned short* arow = Abm + (size_t)(p / 50) * 1024;
  const unsigned short* brow = Aball + (size_t)g16[pf] * 1024;
  char* dst = (char*)Pt2 + (size_t)rt * PT2_RT + mf * 1024 + (t & 63) * 16;
#pragma unroll
  for (int pass = 0; pass < 8; ++pass) {
    int kc = pass * 4 + kcl;
    int k = kc * 32 + oct * 8;
    short8 a8 = *(const short8*)(arow + k);
    short8 b8 = *(const short8*)(brow + k);
    short8 o;
#pragma unroll
    for (int e = 0; e < 8; ++e)
      o[e] = (short)f2bf(bf2f((unsigned short)a8[e]) * bf2f((unsigned short)b8[e]));
    *(short8*)(dst + (size_t)kc * 8192) = o;
  }
  if (t < 128) {
    int kc = 32 + (t >> 6);
    int kpw = (t >> 6) * 32 + oct * 8;
    const float* prow = pw + (size_t)p * 64;
    float4 v0 = *(const float4*)(prow + kpw);
    float4 v1 = *(const float4*)(prow + kpw + 4);
    short8 o;
    o[0] = (short)f2bf(v0.x); o[1] = (short)f2bf(v0.y);
    o[2] = (short)f2bf(v0.z); o[3] = (short)f2bf(v0.w);
    o[4] = (short)f2bf(v1.x); o[5] = (short)f2bf(v1.y);
    o[6] = (short)f2bf(v1.z); o[7] = (short)f2bf(v1.w);
    *(short8*)(dst + (size_t)kc * 8192) = o;
  }
}

// 128x128-per-wave GEMM. Block = 2x2 waves = 256 rows x 256 cols. 1 wave/SIMD.
// MODE 0: Ha+Hb fused store (grid 144 = 36 x * 4 y).
// MODE 1: main GEMM + fused scorer epilogue (grid 800 = 200 x * 4 y, XCD).
template <int MODE>
__global__ __launch_bounds__(256, 1) void k_gt(
    const unsigned short* __restrict__ At, const unsigned short* __restrict__ Bt2,
    float* __restrict__ C, float* __restrict__ partial,
    const float* __restrict__ Hab, const float* __restrict__ b1,
    const float* __restrict__ Wout, const int* __restrict__ idx) {
  constexpr int NKC = MODE ? 34 : 32;
  constexpr size_t ART = MODE ? PT2_RT : MT2_RT;
  int tid = threadIdx.x, lane = tid & 63, wave = tid >> 6;
  int wr = wave >> 1, wc = wave & 1;
  int llo = lane & 15, lhi = lane >> 4;
  int id = blockIdx.x;
  int x, y;
  if (MODE == 1) {
    int r = id >> 3;               // 0..99
    x = (id & 7) * 25 + (r >> 2);  // 25 x-tiles per XCD chunk
    y = r & 3;
  } else {
    x = id >> 2;
    y = id & 3;
  }
  int kcoff = MODE ? 64 : ((x < 32) ? 32 : 0);
  int rt = x * 2 + wr;
  int ct = y * 2 + wc;
  int row0 = rt * 128;
  int n0w = ct * 128;
  const char* pa = (const char*)At + (size_t)rt * ART + lane * 16;
  const char* pb = (const char*)Bt2 + (size_t)ct * BT2_CT + (size_t)kcoff * 8192 + lane * 16;

  f32x4 acc[8][8] = {};
  short8 aA[8], bA[8], aB[8], bB[8];
#pragma unroll
  for (int m = 0; m < 8; ++m) aA[m] = *(const short8*)(pa + m * 1024);
#pragma unroll
  for (int n = 0; n < 8; ++n) bA[n] = *(const short8*)(pb + n * 1024);
  for (int kt = 0; kt < NKC; kt += 2) {
    {
      const char* pa1 = pa + (size_t)(kt + 1) * 8192;
      const char* pb1 = pb + (size_t)(kt + 1) * 8192;
#pragma unroll
      for (int m = 0; m < 8; ++m) aB[m] = *(const short8*)(pa1 + m * 1024);
#pragma unroll
      for (int n = 0; n < 8; ++n) bB[n] = *(const short8*)(pb1 + n * 1024);
    }
#pragma unroll
    for (int m = 0; m < 8; ++m)
#pragma unroll
      for (int n = 0; n < 8; ++n)
        acc[m][n] = __builtin_amdgcn_mfma_f32_16x16x32_bf16(aA[m], bA[n], acc[m][n], 0, 0, 0);
    if (kt + 2 < NKC) {
      const char* pa2 = pa + (size_t)(kt + 2) * 8192;
      const char* pb2 = pb + (size_t)(kt + 2) * 8192;
#pragma unroll
      for (int m = 0; m < 8; ++m) aA[m] = *(const short8*)(pa2 + m * 1024);
#pragma unroll
      for (int n = 0; n < 8; ++n) bA[n] = *(const short8*)(pb2 + n * 1024);
    }
#pragma unroll
    for (int m = 0; m < 8; ++m)
#pragma unroll
      for (int n = 0; n < 8; ++n)
        acc[m][n] = __builtin_amdgcn_mfma_f32_16x16x32_bf16(aB[m], bB[n], acc[m][n], 0, 0, 0);
  }

  if (MODE == 0) {
#pragma unroll
    for (int m = 0; m < 8; ++m)
#pragma unroll
      for (int i = 0; i < 4; ++i) {
        int row = row0 + m * 16 + lhi * 4 + i;
#pragma unroll
        for (int n = 0; n < 8; ++n)
          C[(size_t)row * 1024 + n0w + n * 16 + llo] = acc[m][n][i];
      }
  } else {
    float b1v[8], wov[8];
    int coln[8];
#pragma unroll
    for (int n = 0; n < 8; ++n) {
      coln[n] = n0w + n * 16 + llo;
      b1v[n] = b1[coln[n]];
      wov[n] = Wout[coln[n]];
    }
    int chunk = n0w >> 6;  // y*4 + wc*2; halves +0,+1
#pragma unroll
    for (int m = 0; m < 8; ++m)
#pragma unroll
      for (int i = 0; i < 4; ++i) {
        int p = row0 + m * 16 + lhi * 4 + i;
        int bb = p / 50;
        int gg = idx[p];
        const float* Har = Hab + (size_t)(8192 + bb) * 1024;
        const float* Hbr = Hab + (size_t)gg * 1024;
        float s0 = 0.f, s1 = 0.f;
#pragma unroll
        for (int n = 0; n < 4; ++n) {
          float h = acc[m][n][i] + Har[coln[n]] + Hbr[coln[n]] + b1v[n];
          h = h > 0.f ? h : 0.01f * h;
          s0 += h * wov[n];
        }
#pragma unroll
        for (int n = 4; n < 8; ++n) {
          float h = acc[m][n][i] + Har[coln[n]] + Hbr[coln[n]] + b1v[n];
          h = h > 0.f ? h : 0.01f * h;
          s1 += h * wov[n];
        }
        s0 += __shfl_xor(s0, 1, 64);
        s0 += __shfl_xor(s0, 2, 64);
        s0 += __shfl_xor(s0, 4, 64);
        s0 += __shfl_xor(s0, 8, 64);
        s1 += __shfl_xor(s1, 1, 64);
        s1 += __shfl_xor(s1, 2, 64);
        s1 += __shfl_xor(s1, 4, 64);
        s1 += __shfl_xor(s1, 8, 64);
        if (llo == 0) {
          partial[(size_t)p * 16 + chunk + 0] = s0;
          partial[(size_t)p * 16 + chunk + 1] = s1;
        }
      }
  }
}

__global__ void k_final(const float* __restrict__ partial, const float* __restrict__ rough,
                        const float* __restrict__ bout, float* __restrict__ out) {
  int t = blockIdx.x * 256 + threadIdx.x;
  if (t < 51200) {
    float s = rough[t] + bout[0];
    const float* pp = partial + (size_t)t * 16;
#pragma unroll
    for (int c = 0; c < 16; ++c) s += pp[c];
    out[(size_t)(t / 50) * 51 + 1 + (t % 50)] = s;
  }
  if (t < 1024) out[(size_t)t * 51] = 1e-7f;
}

extern "C" void kernel_launch(void* const* d_in, const int* in_sizes, int n_in,
                              void* d_out, int out_size, void* d_ws, size_t ws_size,
                              hipStream_t stream) {
  (void)in_sizes; (void)n_in; (void)out_size;
  const float* allm  = (const float*)d_in[0];  // [8192][1024]
  const float* am    = (const float*)d_in[1];  // [1024][1024]
  const float* pw    = (const float*)d_in[2];  // [1024][50][64]
  const float* rough = (const float*)d_in[3];  // [1024][50]
  const float* W1    = (const float*)d_in[4];  // [3136][1024]
  const float* b1    = (const float*)d_in[5];  // [1024]
  const float* Wout  = (const float*)d_in[6];  // [1024]
  const float* bout  = (const float*)d_in[7];  // [1]
  const int*   idx   = (const int*)d_in[8];    // [1024][50]
  float* out = (float*)d_out;                  // [1024][51]

  char* w = (char*)d_ws;
  unsigned short* Bt2   = (unsigned short*)w; w += (size_t)8 * BT2_CT;
  unsigned short* Mt2   = (unsigned short*)w; w += (size_t)72 * MT2_RT;
  unsigned short* Abm   = (unsigned short*)w; w += (size_t)1024 * 1024 * 2;
  unsigned short* Aball = (unsigned short*)w; w += (size_t)8192 * 1024 * 2;
  unsigned short* Pt2   = (unsigned short*)w; w += (size_t)400 * PT2_RT;
  float* Hab            = (float*)w;          w += (size_t)9216 * 1024 * 4;
  float* part           = (float*)w;          w += (size_t)51200 * 16 * 4;
  size_t need = (size_t)(w - (char*)d_ws);
  if (ws_size < need) return;

  k_packW<<<dim3(49, 16), 256, 0, stream>>>(W1, Bt2);
  k_cvt<<<dim3(1024), 256, 0, stream>>>(am, Abm, 1024 * 1024 / 4);
  k_cvt<<<dim3(8192), 256, 0, stream>>>(allm, Aball, 8192 * 1024 / 4);
  k_packM<<<dim3(576), 256, 0, stream>>>(am, allm, Mt2);
  k_pairs<<<dim3(3200), 256, 0, stream>>>(Abm, Aball, pw, idx, Pt2);
  // Ha+Hb fused: 9216 rows -> 36 x * 4 y = 144 blocks
  k_gt<0><<<dim3(144), 256, 0, stream>>>(Mt2, Bt2, Hab, nullptr,
                                         nullptr, nullptr, nullptr, nullptr);
  // main: 51200 rows -> 200 x * 4 y = 800 blocks, XCD swizzle
  k_gt<1><<<dim3(800), 256, 0, stream>>>(Pt2, Bt2, nullptr, part,
                                         Hab, b1, Wout, idx);
  k_final<<<dim3(200), 256, 0, stream>>>(part, rough, bout, out);
}

// Round 17
// 247.918 us; speedup vs baseline: 1.3634x; 1.3634x over previous
//
#include <hip/hip_runtime.h>
#include <cstdint>

// ---------------------------------------------------------------------------
// AnaphoricityScorer: scores = rough + FFNN([a, b, a*b, pw] @ W1 -> leaky -> W_out)
// Factorized: h = Ha[batch] + Hb[idx] + (a*b|pw)@W1cd + b1
// R17: R15 (best, 254us) + edge trims. Main/HaHb GEMMs byte-identical to R15
//   (R11/R13/R14/R15/R16 bracket 64x128-per-wave @ 2 waves/SIMD as the
//   MLP x bytes/MFMA optimum; 153-155us is the structural plateau).
//   Trims: k_cvt(am)+Abm dropped (k_pairs reads f32 am with pre-rounding,
//   numerically identical); packW+packM merged into one launch. 8->6 launches.
// ---------------------------------------------------------------------------

typedef short short8 __attribute__((ext_vector_type(8)));
typedef float f32x4 __attribute__((ext_vector_type(4)));

#define BT_STRIDE 100352  // 98 kc * 1024 B per 16-col W1 tile
#define MT_STRIDE 32768   // 32 kc * 1024 B per 16-row mention tile
#define PT_STRIDE 34816   // 34 kc * 1024 B per 16-row pair tile

static __device__ __forceinline__ unsigned short f2bf(float x) {
  union { float f; unsigned u; } v; v.f = x;
  unsigned r = v.u + 0x7fffu + ((v.u >> 16) & 1u);  // RNE
  return (unsigned short)(r >> 16);
}
static __device__ __forceinline__ float bf2f(unsigned short u) {
  union { unsigned u; float f; } v; v.u = ((unsigned)u) << 16;
  return v.f;
}
static __device__ __forceinline__ float rbf(float x) {  // round to bf16 value
  return bf2f(f2bf(x));
}

// Fused packer: blocks 0..783 = W1 -> BtAll tiles; 784..1359 = mentions -> Mt.
__global__ void k_pack(const float* __restrict__ W1, const float* __restrict__ am,
                       const float* __restrict__ allm,
                       unsigned short* __restrict__ BtAll,
                       unsigned short* __restrict__ Mt) {
  int bid = blockIdx.x;
  if (bid < 784) {
    // ---- packW: W1 [3136][1024] f32 -> BtAll [64 ct][98 kc][64 lane][8] ----
    __shared__ float t[64][65];
    int k0 = (bid % 49) * 64, n0 = (bid / 49) * 64;
    int c = threadIdx.x & 63, r4 = threadIdx.x >> 6;
#pragma unroll
    for (int rr = 0; rr < 16; ++rr) {
      int r = rr * 4 + r4;
      t[r][c] = W1[(size_t)(k0 + r) * 1024 + n0 + c];
    }
    __syncthreads();
#pragma unroll
    for (int qq = 0; qq < 2; ++qq) {
      int q = threadIdx.x * 2 + qq;
      int cc = q >> 3, rg = q & 7;
      short8 v;
#pragma unroll
      for (int e = 0; e < 8; ++e) v[e] = (short)f2bf(t[rg * 8 + e][cc]);
      int ct = (n0 + cc) >> 4;
      int kc = (k0 >> 5) + (rg >> 2);
      int ln = (cc & 15) + ((rg & 3) << 4);
      *(short8*)((char*)BtAll + (size_t)ct * BT_STRIDE + kc * 1024 + ln * 16) = v;
    }
  } else {
    // ---- packM: rt 0..511 = allm rows, rt 512..575 = am rows ----
    int rt = bid - 784, t = threadIdx.x;
    const float* S = (rt < 512) ? (allm + (size_t)rt * 16 * 1024)
                                : (am + (size_t)(rt - 512) * 16 * 1024);
    int pf = t & 15, oct = (t >> 4) & 3, kcl = t >> 6;
    const float* row = S + (size_t)pf * 1024;
    char* dst = (char*)Mt + (size_t)rt * MT_STRIDE + (t & 63) * 16;
#pragma unroll
    for (int pass = 0; pass < 8; ++pass) {
      int kc = pass * 4 + kcl;
      int k = kc * 32 + oct * 8;
      float4 v0 = *(const float4*)(row + k);
      float4 v1 = *(const float4*)(row + k + 4);
      short8 o;
      o[0] = (short)f2bf(v0.x); o[1] = (short)f2bf(v0.y);
      o[2] = (short)f2bf(v0.z); o[3] = (short)f2bf(v0.w);
      o[4] = (short)f2bf(v1.x); o[5] = (short)f2bf(v1.y);
      o[6] = (short)f2bf(v1.z); o[7] = (short)f2bf(v1.w);
      *(short8*)(dst + kc * 1024) = o;
    }
  }
}

// f32 -> bf16 row-major (gather source for k_pairs b-rows)
__global__ void k_cvt(const float* __restrict__ s, unsigned short* __restrict__ d, int n4) {
  int i = blockIdx.x * 256 + threadIdx.x;
  if (i < n4) {
    float4 v = ((const float4*)s)[i];
    ushort4 o; o.x = f2bf(v.x); o.y = f2bf(v.y); o.z = f2bf(v.z); o.w = f2bf(v.w);
    ((ushort4*)d)[i] = o;
  }
}

// Pair tiles: block = one rt (16 pairs), coalesced 1KB slab writes.
// a-rows read from f32 am with pre-rounding (== bf16 source numerics).
__global__ void k_pairs(const float* __restrict__ am,
                        const unsigned short* __restrict__ Aball,
                        const float* __restrict__ pw, const int* __restrict__ idx,
                        unsigned short* __restrict__ Pt) {
  __shared__ int g16[16];
  int rt = blockIdx.x, t = threadIdx.x;
  if (t < 16) g16[t] = idx[rt * 16 + t];
  __syncthreads();
  int pf = t & 15, oct = (t >> 4) & 3, kcl = t >> 6;
  int p = rt * 16 + pf;
  const float* arow = am + (size_t)(p / 50) * 1024;
  const unsigned short* brow = Aball + (size_t)g16[pf] * 1024;
  char* dst = (char*)Pt + (size_t)rt * PT_STRIDE + (t & 63) * 16;
#pragma unroll
  for (int pass = 0; pass < 8; ++pass) {
    int kc = pass * 4 + kcl;
    int k = kc * 32 + oct * 8;
    float4 a0 = *(const float4*)(arow + k);
    float4 a1 = *(const float4*)(arow + k + 4);
    short8 b8 = *(const short8*)(brow + k);
    short8 o;
    o[0] = (short)f2bf(rbf(a0.x) * bf2f((unsigned short)b8[0]));
    o[1] = (short)f2bf(rbf(a0.y) * bf2f((unsigned short)b8[1]));
    o[2] = (short)f2bf(rbf(a0.z) * bf2f((unsigned short)b8[2]));
    o[3] = (short)f2bf(rbf(a0.w) * bf2f((unsigned short)b8[3]));
    o[4] = (short)f2bf(rbf(a1.x) * bf2f((unsigned short)b8[4]));
    o[5] = (short)f2bf(rbf(a1.y) * bf2f((unsigned short)b8[5]));
    o[6] = (short)f2bf(rbf(a1.z) * bf2f((unsigned short)b8[6]));
    o[7] = (short)f2bf(rbf(a1.w) * bf2f((unsigned short)b8[7]));
    *(short8*)(dst + kc * 1024) = o;
  }
  if (t < 128) {
    int kc = 32 + (t >> 6);
    int kpw = (t >> 6) * 32 + oct * 8;
    const float* prow = pw + (size_t)p * 64;
    float4 v0 = *(const float4*)(prow + kpw);
    float4 v1 = *(const float4*)(prow + kpw + 4);
    short8 o;
    o[0] = (short)f2bf(v0.x); o[1] = (short)f2bf(v0.y);
    o[2] = (short)f2bf(v0.z); o[3] = (short)f2bf(v0.w);
    o[4] = (short)f2bf(v1.x); o[5] = (short)f2bf(v1.y);
    o[6] = (short)f2bf(v1.z); o[7] = (short)f2bf(v1.w);
    *(short8*)(dst + kc * 1024) = o;
  }
}

// Wave-independent pre-packed GEMM, A-SHARED layout (R15, byte-identical):
// 4 waves cover the SAME 64 rows; wave w owns cols [y*512 + w*128, +128).
// 2-deep reg ping-pong, no LDS, no barriers.
// MODE 0: Ha+Hb fused store (grid 288 = 144 x-tiles * 2 y).
// MODE 1: main GEMM + fused scorer epilogue (grid 1600 = 800 x * 2 y, XCD).
template <int MODE>
__global__ __launch_bounds__(256, 2) void k_gt(
    const unsigned short* __restrict__ At, const unsigned short* __restrict__ BtAll,
    float* __restrict__ C, float* __restrict__ partial,
    const float* __restrict__ Hab, const float* __restrict__ b1,
    const float* __restrict__ Wout, const int* __restrict__ idx) {
  constexpr int NKC = MODE ? 34 : 32;
  constexpr int A_STRIDE = MODE ? PT_STRIDE : MT_STRIDE;
  int tid = threadIdx.x, lane = tid & 63, wave = tid >> 6;
  int llo = lane & 15, lhi = lane >> 4;
  int id = blockIdx.x;
  int x, y;
  if (MODE == 1) {
    int r = id >> 3;                 // 0..199
    x = (id & 7) * 100 + (r >> 1);   // 100 x-tiles per XCD chunk
    y = r & 1;
  } else {
    x = id >> 1;
    y = id & 1;
  }
  int kcoff = MODE ? 64 : ((x < 128) ? 32 : 0);
  int row0 = x * 64;
  int n0w = y * 512 + wave * 128;
  const char* pa = (const char*)At + (size_t)(row0 >> 4) * A_STRIDE + lane * 16;
  const char* pb = (const char*)BtAll + (size_t)(n0w >> 4) * BT_STRIDE +
                   (size_t)kcoff * 1024 + lane * 16;

  f32x4 acc[4][8] = {};
  short8 aA[4], bA[8], aB[4], bB[8];
#pragma unroll
  for (int m = 0; m < 4; ++m) aA[m] = *(const short8*)(pa + (size_t)m * A_STRIDE);
#pragma unroll
  for (int n = 0; n < 8; ++n) bA[n] = *(const short8*)(pb + (size_t)n * BT_STRIDE);
  for (int kt = 0; kt < NKC; kt += 2) {
#pragma unroll
    for (int m = 0; m < 4; ++m)
      aB[m] = *(const short8*)(pa + (size_t)m * A_STRIDE + (kt + 1) * 1024);
#pragma unroll
    for (int n = 0; n < 8; ++n)
      bB[n] = *(const short8*)(pb + (size_t)n * BT_STRIDE + (kt + 1) * 1024);
#pragma unroll
    for (int m = 0; m < 4; ++m)
#pragma unroll
      for (int n = 0; n < 8; ++n)
        acc[m][n] = __builtin_amdgcn_mfma_f32_16x16x32_bf16(aA[m], bA[n], acc[m][n], 0, 0, 0);
    if (kt + 2 < NKC) {
#pragma unroll
      for (int m = 0; m < 4; ++m)
        aA[m] = *(const short8*)(pa + (size_t)m * A_STRIDE + (kt + 2) * 1024);
#pragma unroll
      for (int n = 0; n < 8; ++n)
        bA[n] = *(const short8*)(pb + (size_t)n * BT_STRIDE + (kt + 2) * 1024);
    }
#pragma unroll
    for (int m = 0; m < 4; ++m)
#pragma unroll
      for (int n = 0; n < 8; ++n)
        acc[m][n] = __builtin_amdgcn_mfma_f32_16x16x32_bf16(aB[m], bB[n], acc[m][n], 0, 0, 0);
  }

  if (MODE == 0) {
#pragma unroll
    for (int m = 0; m < 4; ++m)
#pragma unroll
      for (int i = 0; i < 4; ++i) {
        int row = row0 + m * 16 + lhi * 4 + i;
#pragma unroll
        for (int n = 0; n < 8; ++n)
          C[(size_t)row * 1024 + n0w + n * 16 + llo] = acc[m][n][i];
      }
  } else {
    float b1v[8], wov[8];
    int coln[8];
#pragma unroll
    for (int n = 0; n < 8; ++n) {
      coln[n] = n0w + n * 16 + llo;
      b1v[n] = b1[coln[n]];
      wov[n] = Wout[coln[n]];
    }
    int chunk = n0w >> 6;  // y*8 + wave*2
#pragma unroll
    for (int m = 0; m < 4; ++m)
#pragma unroll
      for (int i = 0; i < 4; ++i) {
        int p = row0 + m * 16 + lhi * 4 + i;
        int bb = p / 50;
        int gg = idx[p];
        const float* Har = Hab + (size_t)(8192 + bb) * 1024;
        const float* Hbr = Hab + (size_t)gg * 1024;
        float s0 = 0.f, s1 = 0.f;
#pragma unroll
        for (int n = 0; n < 4; ++n) {
          float h = acc[m][n][i] + Har[coln[n]] + Hbr[coln[n]] + b1v[n];
          h = h > 0.f ? h : 0.01f * h;
          s0 += h * wov[n];
        }
#pragma unroll
        for (int n = 4; n < 8; ++n) {
          float h = acc[m][n][i] + Har[coln[n]] + Hbr[coln[n]] + b1v[n];
          h = h > 0.f ? h : 0.01f * h;
          s1 += h * wov[n];
        }
        s0 += __shfl_xor(s0, 1, 64);
        s0 += __shfl_xor(s0, 2, 64);
        s0 += __shfl_xor(s0, 4, 64);
        s0 += __shfl_xor(s0, 8, 64);
        s1 += __shfl_xor(s1, 1, 64);
        s1 += __shfl_xor(s1, 2, 64);
        s1 += __shfl_xor(s1, 4, 64);
        s1 += __shfl_xor(s1, 8, 64);
        if (llo == 0) {
          partial[(size_t)p * 16 + chunk + 0] = s0;
          partial[(size_t)p * 16 + chunk + 1] = s1;
        }
      }
  }
}

__global__ void k_final(const float* __restrict__ partial, const float* __restrict__ rough,
                        const float* __restrict__ bout, float* __restrict__ out) {
  int t = blockIdx.x * 256 + threadIdx.x;
  if (t < 51200) {
    float s = rough[t] + bout[0];
    const float* pp = partial + (size_t)t * 16;
#pragma unroll
    for (int c = 0; c < 16; ++c) s += pp[c];
    out[(size_t)(t / 50) * 51 + 1 + (t % 50)] = s;
  }
  if (t < 1024) out[(size_t)t * 51] = 1e-7f;
}

extern "C" void kernel_launch(void* const* d_in, const int* in_sizes, int n_in,
                              void* d_out, int out_size, void* d_ws, size_t ws_size,
                              hipStream_t stream) {
  (void)in_sizes; (void)n_in; (void)out_size;
  const float* allm  = (const float*)d_in[0];  // [8192][1024]
  const float* am    = (const float*)d_in[1];  // [1024][1024]
  const float* pw    = (const float*)d_in[2];  // [1024][50][64]
  const float* rough = (const float*)d_in[3];  // [1024][50]
  const float* W1    = (const float*)d_in[4];  // [3136][1024]
  const float* b1    = (const float*)d_in[5];  // [1024]
  const float* Wout  = (const float*)d_in[6];  // [1024]
  const float* bout  = (const float*)d_in[7];  // [1]
  const int*   idx   = (const int*)d_in[8];    // [1024][50]
  float* out = (float*)d_out;                  // [1024][51]

  char* w = (char*)d_ws;
  unsigned short* BtAll = (unsigned short*)w; w += (size_t)64 * BT_STRIDE;
  unsigned short* Mt    = (unsigned short*)w; w += (size_t)576 * MT_STRIDE;
  unsigned short* Aball = (unsigned short*)w; w += (size_t)8192 * 1024 * 2;
  unsigned short* Pt    = (unsigned short*)w; w += (size_t)3200 * PT_STRIDE;
  float* Hab            = (float*)w;          w += (size_t)9216 * 1024 * 4;
  float* part           = (float*)w;          w += (size_t)51200 * 16 * 4;
  size_t need = (size_t)(w - (char*)d_ws);
  if (ws_size < need) return;

  k_pack<<<dim3(1360), 256, 0, stream>>>(W1, am, allm, BtAll, Mt);
  k_cvt<<<dim3(8192), 256, 0, stream>>>(allm, Aball, 8192 * 1024 / 4);
  k_pairs<<<dim3(3200), 256, 0, stream>>>(am, Aball, pw, idx, Pt);
  // Ha+Hb fused: 9216 rows -> 144 x-tiles * 2 y = 288 blocks
  k_gt<0><<<dim3(288), 256, 0, stream>>>(Mt, BtAll, Hab, nullptr,
                                         nullptr, nullptr, nullptr, nullptr);
  // main: 51200 rows -> 800 x * 2 y = 1600 blocks, XCD swizzle
  k_gt<1><<<dim3(1600), 256, 0, stream>>>(Pt, BtAll, nullptr, part,
                                          Hab, b1, Wout, idx);
  k_final<<<dim3(200), 256, 0, stream>>>(part, rough, bout, out);
}

// Round 18
// 227.395 us; speedup vs baseline: 1.4864x; 1.0903x over previous
//
#include <hip/hip_runtime.h>
#include <cstdint>

// ---------------------------------------------------------------------------
// AnaphoricityScorer: scores = rough + FFNN([a, b, a*b, pw] @ W1 -> leaky -> W_out)
// Factorized: h = Ha[batch] + Hb[idx] + (a*b|pw)@W1cd + b1
// R18: R17 + launch fusion for overlap (4 launches):
//   L1 k_prep  = packW (784 blk) + packM (576) + cvt allm (8192)
//   L2 k_mid   = HaHb GEMM (288 blk, issued first) + pairs (3200) -- the
//                return-path-bound GEMM and HBM-bound gather interleave on
//                the CUs instead of running serially (~61us -> ~40us).
//   L3 k_main  = main GEMM (R15-structure, plateau 157us, untouched)
//   L4 k_final
// ---------------------------------------------------------------------------

typedef short short8 __attribute__((ext_vector_type(8)));
typedef float f32x4 __attribute__((ext_vector_type(4)));

#define BT_STRIDE 100352  // 98 kc * 1024 B per 16-col W1 tile
#define MT_STRIDE 32768   // 32 kc * 1024 B per 16-row mention tile
#define PT_STRIDE 34816   // 34 kc * 1024 B per 16-row pair tile

static __device__ __forceinline__ unsigned short f2bf(float x) {
  union { float f; unsigned u; } v; v.f = x;
  unsigned r = v.u + 0x7fffu + ((v.u >> 16) & 1u);  // RNE
  return (unsigned short)(r >> 16);
}
static __device__ __forceinline__ float bf2f(unsigned short u) {
  union { unsigned u; float f; } v; v.u = ((unsigned)u) << 16;
  return v.f;
}
static __device__ __forceinline__ float rbf(float x) {  // round to bf16 value
  return bf2f(f2bf(x));
}

// L1: packW (0..783) + packM (784..1359) + cvt allm (1360..9551)
__global__ __launch_bounds__(256) void k_prep(
    const float* __restrict__ W1, const float* __restrict__ am,
    const float* __restrict__ allm, unsigned short* __restrict__ BtAll,
    unsigned short* __restrict__ Mt, unsigned short* __restrict__ Aball) {
  int bid = blockIdx.x;
  if (bid < 784) {
    __shared__ float t[64][65];
    int k0 = (bid % 49) * 64, n0 = (bid / 49) * 64;
    int c = threadIdx.x & 63, r4 = threadIdx.x >> 6;
#pragma unroll
    for (int rr = 0; rr < 16; ++rr) {
      int r = rr * 4 + r4;
      t[r][c] = W1[(size_t)(k0 + r) * 1024 + n0 + c];
    }
    __syncthreads();
#pragma unroll
    for (int qq = 0; qq < 2; ++qq) {
      int q = threadIdx.x * 2 + qq;
      int cc = q >> 3, rg = q & 7;
      short8 v;
#pragma unroll
      for (int e = 0; e < 8; ++e) v[e] = (short)f2bf(t[rg * 8 + e][cc]);
      int ct = (n0 + cc) >> 4;
      int kc = (k0 >> 5) + (rg >> 2);
      int ln = (cc & 15) + ((rg & 3) << 4);
      *(short8*)((char*)BtAll + (size_t)ct * BT_STRIDE + kc * 1024 + ln * 16) = v;
    }
  } else if (bid < 1360) {
    int rt = bid - 784, t = threadIdx.x;
    const float* S = (rt < 512) ? (allm + (size_t)rt * 16 * 1024)
                                : (am + (size_t)(rt - 512) * 16 * 1024);
    int pf = t & 15, oct = (t >> 4) & 3, kcl = t >> 6;
    const float* row = S + (size_t)pf * 1024;
    char* dst = (char*)Mt + (size_t)rt * MT_STRIDE + (t & 63) * 16;
#pragma unroll
    for (int pass = 0; pass < 8; ++pass) {
      int kc = pass * 4 + kcl;
      int k = kc * 32 + oct * 8;
      float4 v0 = *(const float4*)(row + k);
      float4 v1 = *(const float4*)(row + k + 4);
      short8 o;
      o[0] = (short)f2bf(v0.x); o[1] = (short)f2bf(v0.y);
      o[2] = (short)f2bf(v0.z); o[3] = (short)f2bf(v0.w);
      o[4] = (short)f2bf(v1.x); o[5] = (short)f2bf(v1.y);
      o[6] = (short)f2bf(v1.z); o[7] = (short)f2bf(v1.w);
      *(short8*)(dst + kc * 1024) = o;
    }
  } else {
    int i = (bid - 1360) * 256 + threadIdx.x;  // float4 index
    if (i < 8192 * 1024 / 4) {
      float4 v = ((const float4*)allm)[i];
      ushort4 o; o.x = f2bf(v.x); o.y = f2bf(v.y); o.z = f2bf(v.z); o.w = f2bf(v.w);
      ((ushort4*)Aball)[i] = o;
    }
  }
}

// HaHb GEMM body (R15 A-shared layout, MODE 0): id in [0,288)
static __device__ __forceinline__ void gt0_body(
    int id, const unsigned short* __restrict__ Mt,
    const unsigned short* __restrict__ BtAll, float* __restrict__ Hab) {
  int tid = threadIdx.x, lane = tid & 63, wave = tid >> 6;
  int llo = lane & 15, lhi = lane >> 4;
  int x = id >> 1, y = id & 1;
  int kcoff = (x < 128) ? 32 : 0;
  int row0 = x * 64;
  int n0w = y * 512 + wave * 128;
  const char* pa = (const char*)Mt + (size_t)(row0 >> 4) * MT_STRIDE + lane * 16;
  const char* pb = (const char*)BtAll + (size_t)(n0w >> 4) * BT_STRIDE +
                   (size_t)kcoff * 1024 + lane * 16;
  f32x4 acc[4][8] = {};
  short8 aA[4], bA[8], aB[4], bB[8];
#pragma unroll
  for (int m = 0; m < 4; ++m) aA[m] = *(const short8*)(pa + (size_t)m * MT_STRIDE);
#pragma unroll
  for (int n = 0; n < 8; ++n) bA[n] = *(const short8*)(pb + (size_t)n * BT_STRIDE);
  for (int kt = 0; kt < 32; kt += 2) {
#pragma unroll
    for (int m = 0; m < 4; ++m)
      aB[m] = *(const short8*)(pa + (size_t)m * MT_STRIDE + (kt + 1) * 1024);
#pragma unroll
    for (int n = 0; n < 8; ++n)
      bB[n] = *(const short8*)(pb + (size_t)n * BT_STRIDE + (kt + 1) * 1024);
#pragma unroll
    for (int m = 0; m < 4; ++m)
#pragma unroll
      for (int n = 0; n < 8; ++n)
        acc[m][n] = __builtin_amdgcn_mfma_f32_16x16x32_bf16(aA[m], bA[n], acc[m][n], 0, 0, 0);
    if (kt + 2 < 32) {
#pragma unroll
      for (int m = 0; m < 4; ++m)
        aA[m] = *(const short8*)(pa + (size_t)m * MT_STRIDE + (kt + 2) * 1024);
#pragma unroll
      for (int n = 0; n < 8; ++n)
        bA[n] = *(const short8*)(pb + (size_t)n * BT_STRIDE + (kt + 2) * 1024);
    }
#pragma unroll
    for (int m = 0; m < 4; ++m)
#pragma unroll
      for (int n = 0; n < 8; ++n)
        acc[m][n] = __builtin_amdgcn_mfma_f32_16x16x32_bf16(aB[m], bB[n], acc[m][n], 0, 0, 0);
  }
#pragma unroll
  for (int m = 0; m < 4; ++m)
#pragma unroll
    for (int i = 0; i < 4; ++i) {
      int row = row0 + m * 16 + lhi * 4 + i;
#pragma unroll
      for (int n = 0; n < 8; ++n)
        Hab[(size_t)row * 1024 + n0w + n * 16 + llo] = acc[m][n][i];
    }
}

// Pair-tile body: rt in [0,3200)
static __device__ __forceinline__ void pairs_body(
    int rt, const float* __restrict__ am, const unsigned short* __restrict__ Aball,
    const float* __restrict__ pw, const int* __restrict__ idx,
    unsigned short* __restrict__ Pt) {
  __shared__ int g16[16];
  int t = threadIdx.x;
  if (t < 16) g16[t] = idx[rt * 16 + t];
  __syncthreads();
  int pf = t & 15, oct = (t >> 4) & 3, kcl = t >> 6;
  int p = rt * 16 + pf;
  const float* arow = am + (size_t)(p / 50) * 1024;
  const unsigned short* brow = Aball + (size_t)g16[pf] * 1024;
  char* dst = (char*)Pt + (size_t)rt * PT_STRIDE + (t & 63) * 16;
#pragma unroll
  for (int pass = 0; pass < 8; ++pass) {
    int kc = pass * 4 + kcl;
    int k = kc * 32 + oct * 8;
    float4 a0 = *(const float4*)(arow + k);
    float4 a1 = *(const float4*)(arow + k + 4);
    short8 b8 = *(const short8*)(brow + k);
    short8 o;
    o[0] = (short)f2bf(rbf(a0.x) * bf2f((unsigned short)b8[0]));
    o[1] = (short)f2bf(rbf(a0.y) * bf2f((unsigned short)b8[1]));
    o[2] = (short)f2bf(rbf(a0.z) * bf2f((unsigned short)b8[2]));
    o[3] = (short)f2bf(rbf(a0.w) * bf2f((unsigned short)b8[3]));
    o[4] = (short)f2bf(rbf(a1.x) * bf2f((unsigned short)b8[4]));
    o[5] = (short)f2bf(rbf(a1.y) * bf2f((unsigned short)b8[5]));
    o[6] = (short)f2bf(rbf(a1.z) * bf2f((unsigned short)b8[6]));
    o[7] = (short)f2bf(rbf(a1.w) * bf2f((unsigned short)b8[7]));
    *(short8*)(dst + kc * 1024) = o;
  }
  if (t < 128) {
    int kc = 32 + (t >> 6);
    int kpw = (t >> 6) * 32 + oct * 8;
    const float* prow = pw + (size_t)p * 64;
    float4 v0 = *(const float4*)(prow + kpw);
    float4 v1 = *(const float4*)(prow + kpw + 4);
    short8 o;
    o[0] = (short)f2bf(v0.x); o[1] = (short)f2bf(v0.y);
    o[2] = (short)f2bf(v0.z); o[3] = (short)f2bf(v0.w);
    o[4] = (short)f2bf(v1.x); o[5] = (short)f2bf(v1.y);
    o[6] = (short)f2bf(v1.z); o[7] = (short)f2bf(v1.w);
    *(short8*)(dst + kc * 1024) = o;
  }
}

// L2: heterogeneous — blocks 0..287 = HaHb GEMM, 288..3487 = pair tiles.
__global__ __launch_bounds__(256, 2) void k_mid(
    const unsigned short* __restrict__ Mt, const unsigned short* __restrict__ BtAll,
    float* __restrict__ Hab, const float* __restrict__ am,
    const unsigned short* __restrict__ Aball, const float* __restrict__ pw,
    const int* __restrict__ idx, unsigned short* __restrict__ Pt) {
  if (blockIdx.x < 288) gt0_body(blockIdx.x, Mt, BtAll, Hab);
  else pairs_body(blockIdx.x - 288, am, Aball, pw, idx, Pt);
}

// L3: main GEMM (R15 A-shared, 2-deep ping-pong, no LDS/barriers) + epilogue.
__global__ __launch_bounds__(256, 2) void k_main(
    const unsigned short* __restrict__ Pt, const unsigned short* __restrict__ BtAll,
    float* __restrict__ partial, const float* __restrict__ Hab,
    const float* __restrict__ b1, const float* __restrict__ Wout,
    const int* __restrict__ idx) {
  int tid = threadIdx.x, lane = tid & 63, wave = tid >> 6;
  int llo = lane & 15, lhi = lane >> 4;
  int id = blockIdx.x;
  int r = id >> 3;                 // 0..199
  int x = (id & 7) * 100 + (r >> 1);
  int y = r & 1;
  int row0 = x * 64;
  int n0w = y * 512 + wave * 128;
  const char* pa = (const char*)Pt + (size_t)(row0 >> 4) * PT_STRIDE + lane * 16;
  const char* pb = (const char*)BtAll + (size_t)(n0w >> 4) * BT_STRIDE +
                   (size_t)64 * 1024 + lane * 16;

  f32x4 acc[4][8] = {};
  short8 aA[4], bA[8], aB[4], bB[8];
#pragma unroll
  for (int m = 0; m < 4; ++m) aA[m] = *(const short8*)(pa + (size_t)m * PT_STRIDE);
#pragma unroll
  for (int n = 0; n < 8; ++n) bA[n] = *(const short8*)(pb + (size_t)n * BT_STRIDE);
  for (int kt = 0; kt < 34; kt += 2) {
#pragma unroll
    for (int m = 0; m < 4; ++m)
      aB[m] = *(const short8*)(pa + (size_t)m * PT_STRIDE + (kt + 1) * 1024);
#pragma unroll
    for (int n = 0; n < 8; ++n)
      bB[n] = *(const short8*)(pb + (size_t)n * BT_STRIDE + (kt + 1) * 1024);
#pragma unroll
    for (int m = 0; m < 4; ++m)
#pragma unroll
      for (int n = 0; n < 8; ++n)
        acc[m][n] = __builtin_amdgcn_mfma_f32_16x16x32_bf16(aA[m], bA[n], acc[m][n], 0, 0, 0);
    if (kt + 2 < 34) {
#pragma unroll
      for (int m = 0; m < 4; ++m)
        aA[m] = *(const short8*)(pa + (size_t)m * PT_STRIDE + (kt + 2) * 1024);
#pragma unroll
      for (int n = 0; n < 8; ++n)
        bA[n] = *(const short8*)(pb + (size_t)n * BT_STRIDE + (kt + 2) * 1024);
    }
#pragma unroll
    for (int m = 0; m < 4; ++m)
#pragma unroll
      for (int n = 0; n < 8; ++n)
        acc[m][n] = __builtin_amdgcn_mfma_f32_16x16x32_bf16(aB[m], bB[n], acc[m][n], 0, 0, 0);
  }

  float b1v[8], wov[8];
  int coln[8];
#pragma unroll
  for (int n = 0; n < 8; ++n) {
    coln[n] = n0w + n * 16 + llo;
    b1v[n] = b1[coln[n]];
    wov[n] = Wout[coln[n]];
  }
  int chunk = n0w >> 6;  // y*8 + wave*2
#pragma unroll
  for (int m = 0; m < 4; ++m)
#pragma unroll
    for (int i = 0; i < 4; ++i) {
      int p = row0 + m * 16 + lhi * 4 + i;
      int bb = p / 50;
      int gg = idx[p];
      const float* Har = Hab + (size_t)(8192 + bb) * 1024;
      const float* Hbr = Hab + (size_t)gg * 1024;
      float s0 = 0.f, s1 = 0.f;
#pragma unroll
      for (int n = 0; n < 4; ++n) {
        float h = acc[m][n][i] + Har[coln[n]] + Hbr[coln[n]] + b1v[n];
        h = h > 0.f ? h : 0.01f * h;
        s0 += h * wov[n];
      }
#pragma unroll
      for (int n = 4; n < 8; ++n) {
        float h = acc[m][n][i] + Har[coln[n]] + Hbr[coln[n]] + b1v[n];
        h = h > 0.f ? h : 0.01f * h;
        s1 += h * wov[n];
      }
      s0 += __shfl_xor(s0, 1, 64);
      s0 += __shfl_xor(s0, 2, 64);
      s0 += __shfl_xor(s0, 4, 64);
      s0 += __shfl_xor(s0, 8, 64);
      s1 += __shfl_xor(s1, 1, 64);
      s1 += __shfl_xor(s1, 2, 64);
      s1 += __shfl_xor(s1, 4, 64);
      s1 += __shfl_xor(s1, 8, 64);
      if (llo == 0) {
        partial[(size_t)p * 16 + chunk + 0] = s0;
        partial[(size_t)p * 16 + chunk + 1] = s1;
      }
    }
}

__global__ void k_final(const float* __restrict__ partial, const float* __restrict__ rough,
                        const float* __restrict__ bout, float* __restrict__ out) {
  int t = blockIdx.x * 256 + threadIdx.x;
  if (t < 51200) {
    float s = rough[t] + bout[0];
    const float* pp = partial + (size_t)t * 16;
#pragma unroll
    for (int c = 0; c < 16; ++c) s += pp[c];
    out[(size_t)(t / 50) * 51 + 1 + (t % 50)] = s;
  }
  if (t < 1024) out[(size_t)t * 51] = 1e-7f;
}

extern "C" void kernel_launch(void* const* d_in, const int* in_sizes, int n_in,
                              void* d_out, int out_size, void* d_ws, size_t ws_size,
                              hipStream_t stream) {
  (void)in_sizes; (void)n_in; (void)out_size;
  const float* allm  = (const float*)d_in[0];  // [8192][1024]
  const float* am    = (const float*)d_in[1];  // [1024][1024]
  const float* pw    = (const float*)d_in[2];  // [1024][50][64]
  const float* rough = (const float*)d_in[3];  // [1024][50]
  const float* W1    = (const float*)d_in[4];  // [3136][1024]
  const float* b1    = (const float*)d_in[5];  // [1024]
  const float* Wout  = (const float*)d_in[6];  // [1024]
  const float* bout  = (const float*)d_in[7];  // [1]
  const int*   idx   = (const int*)d_in[8];    // [1024][50]
  float* out = (float*)d_out;                  // [1024][51]

  char* w = (char*)d_ws;
  unsigned short* BtAll = (unsigned short*)w; w += (size_t)64 * BT_STRIDE;
  unsigned short* Mt    = (unsigned short*)w; w += (size_t)576 * MT_STRIDE;
  unsigned short* Aball = (unsigned short*)w; w += (size_t)8192 * 1024 * 2;
  unsigned short* Pt    = (unsigned short*)w; w += (size_t)3200 * PT_STRIDE;
  float* Hab            = (float*)w;          w += (size_t)9216 * 1024 * 4;
  float* part           = (float*)w;          w += (size_t)51200 * 16 * 4;
  size_t need = (size_t)(w - (char*)d_ws);
  if (ws_size < need) return;

  k_prep<<<dim3(9552), 256, 0, stream>>>(W1, am, allm, BtAll, Mt, Aball);
  k_mid<<<dim3(3488), 256, 0, stream>>>(Mt, BtAll, Hab, am, Aball, pw, idx, Pt);
  k_main<<<dim3(1600), 256, 0, stream>>>(Pt, BtAll, part, Hab, b1, Wout, idx);
  k_final<<<dim3(200), 256, 0, stream>>>(part, rough, bout, out);
}